// Round 2
// baseline (854.191 us; speedup 1.0000x reference)
//
#include <hip/hip_runtime.h>

// Problem dims (fixed by reference)
#define S_DIM 2048
#define B_DIM 32
#define H_DIM 1024
#define ROWS  (S_DIM * B_DIM)   // 65536 GEMM rows, row = s*32 + b

typedef __attribute__((ext_vector_type(8))) short s16x8;  // 8 bf16 (4 VGPRs) MFMA operand
typedef __attribute__((ext_vector_type(4))) float f32x4;  // MFMA accumulator

// ---- helpers ----------------------------------------------------------------

// Pack two fp32 -> u32 [bf16(a) | bf16(b)<<16], round-half-up (+0x8000, perm).
__device__ __forceinline__ unsigned pack2_bf16(float a, float b) {
  unsigned ua = __float_as_uint(a) + 0x8000u;
  unsigned ub = __float_as_uint(b) + 0x8000u;
  return __builtin_amdgcn_perm(ub, ua, 0x07060302u);
}

__device__ __forceinline__ unsigned short bf16_rne(float f) {
  unsigned u = __float_as_uint(f);
  return (unsigned short)((u + 0x7FFFu + ((u >> 16) & 1u)) >> 16);
}

__device__ __forceinline__ float bf16_to_f32(unsigned short s) {
  return __uint_as_float((unsigned)s << 16);
}

// tanh via one v_exp_f32
__device__ __forceinline__ float fast_tanh(float x) {
  x = fminf(15.0f, fmaxf(-15.0f, x));
  float z = __expf(-2.0f * x);
  return (1.0f - z) * __builtin_amdgcn_rcpf(1.0f + z);
}

// async global->LDS, 16B/lane. LDS dest must be wave-uniform base + lane*16.
__device__ __forceinline__ void load_lds16(const void* g, void* l) {
  __builtin_amdgcn_global_load_lds(
      (const __attribute__((address_space(1))) unsigned int*)g,
      (__attribute__((address_space(3))) unsigned int*)l, 16, 0, 0);
}

// ---- K0: convert enc (S,B,H) fp32 -> bf16 (same layout), RNE -----------------
__global__ void conv_bf16_kernel(const float* __restrict__ enc,
                                 unsigned short* __restrict__ Ep) {
  size_t idx = (size_t)blockIdx.x * 256 + threadIdx.x;  // 8M threads x 8 elems
  size_t base = idx * 8;
  f32x4 a0 = *(const f32x4*)(enc + base);
  f32x4 a1 = *(const f32x4*)(enc + base + 4);
  union { s16x8 v; unsigned short u[8]; } o;
  o.u[0] = bf16_rne(a0.x); o.u[1] = bf16_rne(a0.y);
  o.u[2] = bf16_rne(a0.z); o.u[3] = bf16_rne(a0.w);
  o.u[4] = bf16_rne(a1.x); o.u[5] = bf16_rne(a1.y);
  o.u[6] = bf16_rne(a1.z); o.u[7] = bf16_rne(a1.w);
  *(s16x8*)(Ep + base) = o.v;
}

// ---- K1: hid_proj[b][h] = hidden[b,:] . attn_w[h, 0:H] + attn_b[h] (fp32) ----
// 64 blocks x 16 h each; W rows cached in registers, attn_w read exactly once.
__global__ void hidproj_kernel(const float* __restrict__ hidden,
                               const float* __restrict__ attn_w,
                               const float* __restrict__ attn_b,
                               float* __restrict__ hp) {
  int tid = threadIdx.x;
  int hl  = tid >> 4;            // 0..15
  int kp  = tid & 15;            // 16-way k-split, low bits -> shfl group
  int h   = blockIdx.x * 16 + hl;
  const f32x4* wrow = (const f32x4*)(attn_w + (size_t)h * (2 * H_DIM)) + kp * 16;
  f32x4 w[16];
#pragma unroll
  for (int j = 0; j < 16; ++j) w[j] = wrow[j];
  float bias = attn_b[h];
  for (int b = 0; b < B_DIM; ++b) {
    const f32x4* xrow = (const f32x4*)(hidden + (size_t)b * H_DIM) + kp * 16;
    float s = 0.f;
#pragma unroll
    for (int j = 0; j < 16; ++j) {
      f32x4 x = xrow[j];
      s = fmaf(w[j].x, x.x, s); s = fmaf(w[j].y, x.y, s);
      s = fmaf(w[j].z, x.z, s); s = fmaf(w[j].w, x.w, s);
    }
    s += __shfl_xor(s, 1); s += __shfl_xor(s, 2);
    s += __shfl_xor(s, 4); s += __shfl_xor(s, 8);
    if (kp == 0) hp[(size_t)b * H_DIM + h] = s + bias;
  }
}

// ---- K2: pack W2 = attn_w[:, H:2H] to bf16, layout [h][k] (MFMA B layout) ----
__global__ void packW2_kernel(const float* __restrict__ attn_w,
                              unsigned short* __restrict__ Bp) {
  int idx = blockIdx.x * 256 + threadIdx.x;
  int h  = idx >> 8;
  int kc = idx & 255;
  f32x4 w = *(const f32x4*)(attn_w + (size_t)h * (2 * H_DIM) + H_DIM + kc * 4);
  ushort4 o;
  o.x = bf16_rne(w.x); o.y = bf16_rne(w.y); o.z = bf16_rne(w.z); o.w = bf16_rne(w.w);
  *(ushort4*)(Bp + (size_t)h * H_DIM + kc * 4) = o;
}

// ---- K3: fused GEMM(enc x W2^T) + tanh + dot-v -> scores (atomic partials) ---
// Tile 128 rows x 256 cols, BK=32, 512 threads = 8 waves in 2x4; wave = 64x64
// (acc 4x4 frags = 64 AGPR -> combined regs <=128 -> 4 waves/SIMD).
// LDS layouts are 16B-chunk-flat (DMA lane-contiguity) AND give 2-way-free
// fragment reads: As16[kc][r][8] bank=(r*4)%32, Bs[kb][n][8] bank=(n*4)%32.
template <bool ABF16>
__global__ __launch_bounds__(512, 4)
void gemm_scores_kernel(const float* __restrict__ encf,
                        const unsigned short* __restrict__ encb,
                        const unsigned short* __restrict__ Bp,
                        const float* __restrict__ hp,
                        const float* __restrict__ v,
                        float* __restrict__ scores) {
  __shared__ __align__(16) unsigned short Bs[4][256][8];       // 16 KiB
  __shared__ __align__(16) char AsRaw[ABF16 ? 8192 : 16384];   // 8 or 16 KiB
  auto* As16 = (unsigned short(*)[128][8])AsRaw;  // [4][128][8] bf16
  auto* As32 = (float(*)[128][4])AsRaw;           // [8][128][4] fp32

  const int tid  = threadIdx.x;
  const int lane = tid & 63;
  const int wid  = tid >> 6;     // 0..7
  const int wm   = wid >> 2;     // row half (0..1), 64 rows
  const int wn   = wid & 3;      // col quarter (0..3), 64 cols
  const int m16  = lane & 15;
  const int quad = lane >> 4;
  const int row0 = blockIdx.y * 128;
  const int n0   = blockIdx.x * 256;

  f32x4 acc[4][4];
#pragma unroll
  for (int i = 0; i < 4; ++i)
#pragma unroll
    for (int j = 0; j < 4; ++j) acc[i][j] = (f32x4){0.f, 0.f, 0.f, 0.f};

  for (int k0 = 0; k0 < H_DIM; k0 += 32) {
    if constexpr (ABF16) {
      // A: 512 chunks of 16B (128 rows x 32 bf16), 1 per thread
      int r = tid & 127, kc = tid >> 7;
      load_lds16(encb + (size_t)(row0 + r) * H_DIM + k0 + kc * 8, &As16[kc][r][0]);
    } else {
#pragma unroll
      for (int c = 0; c < 2; ++c) {   // 1024 chunks (128 rows x 32 fp32)
        int q = c * 512 + tid, r = q & 127, kc = q >> 7;
        load_lds16(encf + (size_t)(row0 + r) * H_DIM + k0 + kc * 4, &As32[kc][r][0]);
      }
    }
#pragma unroll
    for (int c = 0; c < 2; ++c) {     // B: 1024 chunks (256 cols x 32 bf16)
      int q = c * 512 + tid, n = q & 255, kb = q >> 8;
      load_lds16(Bp + (size_t)(n0 + n) * H_DIM + k0 + kb * 8, &Bs[kb][n][0]);
    }
    __syncthreads();

    s16x8 af[4], bf[4];
#pragma unroll
    for (int mf = 0; mf < 4; ++mf) {
      int r = wm * 64 + mf * 16 + m16;
      if constexpr (ABF16) {
        af[mf] = *(const s16x8*)&As16[quad][r][0];           // k = quad*8+0..7
      } else {
        f32x4 a0 = *(const f32x4*)&As32[quad * 2][r][0];
        f32x4 a1 = *(const f32x4*)&As32[quad * 2 + 1][r][0];
        union { s16x8 v8; unsigned u[4]; } pk;
        pk.u[0] = pack2_bf16(a0.x, a0.y);
        pk.u[1] = pack2_bf16(a0.z, a0.w);
        pk.u[2] = pack2_bf16(a1.x, a1.y);
        pk.u[3] = pack2_bf16(a1.z, a1.w);
        af[mf] = pk.v8;
      }
    }
#pragma unroll
    for (int nf = 0; nf < 4; ++nf) {
      int n = wn * 64 + nf * 16 + m16;
      bf[nf] = *(const s16x8*)&Bs[quad][n][0];               // k = quad*8+0..7
    }
#pragma unroll
    for (int mf = 0; mf < 4; ++mf)
#pragma unroll
      for (int nf = 0; nf < 4; ++nf)
        acc[mf][nf] = __builtin_amdgcn_mfma_f32_16x16x32_bf16(
            af[mf], bf[nf], acc[mf][nf], 0, 0, 0);
    __syncthreads();
  }

  // Epilogue: energy = tanh(acc + hid_proj(incl. bias)); partial score =
  // sum over this wave's 64 cols of energy*v; one atomic per row-frag.
  // C/D layout: col = lane&15, row = quad*4+reg.
#pragma unroll
  for (int mf = 0; mf < 4; ++mf) {
#pragma unroll
    for (int reg = 0; reg < 4; ++reg) {
      int row_g = row0 + wm * 64 + mf * 16 + quad * 4 + reg;
      int b     = row_g & 31;     // row = s*32 + b
      int s     = row_g >> 5;
      float psum = 0.f;
#pragma unroll
      for (int nf = 0; nf < 4; ++nf) {
        int col = n0 + wn * 64 + nf * 16 + m16;
        float e = acc[mf][nf][reg] + hp[b * H_DIM + col];
        e = fast_tanh(e);
        psum = fmaf(e, v[col], psum);
      }
      psum += __shfl_xor(psum, 1);
      psum += __shfl_xor(psum, 2);
      psum += __shfl_xor(psum, 4);
      psum += __shfl_xor(psum, 8);
      if (m16 == 0) atomicAdd(&scores[b * S_DIM + s], psum);
    }
  }
}

// ---- K4: masked softmax over s per batch row -> attention weights ------------
__global__ void softmax_kernel(const float* __restrict__ scores,
                               const int* __restrict__ lens,
                               float* __restrict__ wout) {
  int b = blockIdx.x, tid = threadIdx.x;
  int len = lens[b];
  float vals[8];
  float m = -3.0e38f;
#pragma unroll
  for (int i = 0; i < 8; ++i) {
    int s = i * 256 + tid;
    float x = scores[b * S_DIM + s];
    vals[i] = (s < len) ? x : -3.0e38f;
    m = fmaxf(m, vals[i]);
  }
#pragma unroll
  for (int off = 32; off > 0; off >>= 1) m = fmaxf(m, __shfl_xor(m, off));
  __shared__ float redm[4], reds[4];
  int wid = tid >> 6, lane = tid & 63;
  if (lane == 0) redm[wid] = m;
  __syncthreads();
  m = fmaxf(fmaxf(redm[0], redm[1]), fmaxf(redm[2], redm[3]));

  float e[8];
  float sum = 0.f;
#pragma unroll
  for (int i = 0; i < 8; ++i) {
    int s = i * 256 + tid;
    e[i] = (s < len) ? __expf(vals[i] - m) : 0.f;  // masked -> exactly 0
    sum += e[i];
  }
#pragma unroll
  for (int off = 32; off > 0; off >>= 1) sum += __shfl_xor(sum, off);
  if (lane == 0) reds[wid] = sum;
  __syncthreads();
  sum = reds[0] + reds[1] + reds[2] + reds[3];
  float inv = 1.0f / sum;
#pragma unroll
  for (int i = 0; i < 8; ++i)
    wout[b * S_DIM + i * 256 + tid] = e[i] * inv;
}

// ---- K5: context[b][h] = sum_s w[b][s] * enc[s][b][h] ------------------------
// Block-level prefix skip (mask is a prefix); no per-i branch (w==0 exact).
template <bool BF16>
__global__ void context_kernel(const float* __restrict__ encf,
                               const unsigned short* __restrict__ encb,
                               const float* __restrict__ wts,
                               const int* __restrict__ lens,
                               float* __restrict__ ctx) {
  int sc = blockIdx.x;            // 32 chunks of 64 s
  int b  = blockIdx.y;
  int len = lens[b];
  int s0 = sc * 64;
  if (s0 >= len) return;          // fully masked chunk, weights all zero
  int cnt = min(64, len - s0);
  int tid = threadIdx.x;          // 256 threads x 4 h = 1024
  f32x4 acc = (f32x4){0.f, 0.f, 0.f, 0.f};
  const float* wrow = wts + (size_t)b * S_DIM + s0;
#pragma unroll 4
  for (int i = 0; i < cnt; ++i) {
    float w = wrow[i];
    size_t base = ((size_t)(s0 + i) * B_DIM + b) * H_DIM + tid * 4;
    if constexpr (BF16) {
      ushort4 e = *(const ushort4*)(encb + base);
      acc.x = fmaf(w, bf16_to_f32(e.x), acc.x);
      acc.y = fmaf(w, bf16_to_f32(e.y), acc.y);
      acc.z = fmaf(w, bf16_to_f32(e.z), acc.z);
      acc.w = fmaf(w, bf16_to_f32(e.w), acc.w);
    } else {
      f32x4 e = *(const f32x4*)(encf + base);
      acc.x = fmaf(w, e.x, acc.x);
      acc.y = fmaf(w, e.y, acc.y);
      acc.z = fmaf(w, e.z, acc.z);
      acc.w = fmaf(w, e.w, acc.w);
    }
  }
  float* dst = ctx + (size_t)b * H_DIM + tid * 4;
  atomicAdd(dst + 0, acc.x);
  atomicAdd(dst + 1, acc.y);
  atomicAdd(dst + 2, acc.z);
  atomicAdd(dst + 3, acc.w);
}

// ---- launch -----------------------------------------------------------------
extern "C" void kernel_launch(void* const* d_in, const int* in_sizes, int n_in,
                              void* d_out, int out_size, void* d_ws, size_t ws_size,
                              hipStream_t stream) {
  const float* hidden = (const float*)d_in[0];   // (B,H)
  const float* enc    = (const float*)d_in[1];   // (S,B,H)
  const int*   lens   = (const int*)d_in[2];     // (B,)
  const float* attn_w = (const float*)d_in[3];   // (H,2H)
  const float* attn_b = (const float*)d_in[4];   // (H,)
  const float* v      = (const float*)d_in[5];   // (H,)

  float* out_ctx = (float*)d_out;                      // B*H context
  float* out_w   = (float*)d_out + B_DIM * H_DIM;      // B*S weights

  const size_t epBytes = (size_t)ROWS * H_DIM * 2;     // 128 MiB bf16 enc
  const size_t scBytes = (size_t)B_DIM * S_DIM * 4;
  const size_t hpBytes = (size_t)B_DIM * H_DIM * 4;
  const size_t bpBytes = (size_t)H_DIM * H_DIM * 2;
  bool bf16path = ws_size >= epBytes + scBytes + hpBytes + bpBytes + 256;

  char* p = (char*)d_ws;
  unsigned short* Ep = nullptr;
  if (bf16path) { Ep = (unsigned short*)p; p += epBytes; }
  float* scores = (float*)p; p += scBytes;
  float* hp     = (float*)p; p += hpBytes;
  unsigned short* Bp = (unsigned short*)p;

  hipMemsetAsync(scores, 0, scBytes, stream);
  hipMemsetAsync(out_ctx, 0, (size_t)B_DIM * H_DIM * sizeof(float), stream);

  if (bf16path)
    hipLaunchKernelGGL(conv_bf16_kernel, dim3(ROWS * H_DIM / 8 / 256), dim3(256),
                       0, stream, enc, Ep);
  hipLaunchKernelGGL(hidproj_kernel, dim3(H_DIM / 16), dim3(256), 0, stream,
                     hidden, attn_w, attn_b, hp);
  hipLaunchKernelGGL(packW2_kernel, dim3((H_DIM * H_DIM / 4) / 256), dim3(256),
                     0, stream, attn_w, Bp);
  if (bf16path)
    hipLaunchKernelGGL((gemm_scores_kernel<true>), dim3(H_DIM / 256, ROWS / 128),
                       dim3(512), 0, stream, enc, Ep, Bp, hp, v, scores);
  else
    hipLaunchKernelGGL((gemm_scores_kernel<false>), dim3(H_DIM / 256, ROWS / 128),
                       dim3(512), 0, stream, enc, Ep, Bp, hp, v, scores);
  hipLaunchKernelGGL(softmax_kernel, dim3(B_DIM), dim3(256), 0, stream,
                     scores, lens, out_w);
  if (bf16path)
    hipLaunchKernelGGL((context_kernel<true>), dim3(S_DIM / 64, B_DIM), dim3(256),
                       0, stream, enc, Ep, out_w, lens, out_ctx);
  else
    hipLaunchKernelGGL((context_kernel<false>), dim3(S_DIM / 64, B_DIM), dim3(256),
                       0, stream, enc, Ep, out_w, lens, out_ctx);
}

// Round 3
// 805.755 us; speedup vs baseline: 1.0601x; 1.0601x over previous
//
#include <hip/hip_runtime.h>

// Problem dims (fixed by reference)
#define S_DIM 2048
#define B_DIM 32
#define H_DIM 1024
#define ROWS  (S_DIM * B_DIM)   // 65536 GEMM rows, row = s*32 + b

typedef __attribute__((ext_vector_type(4))) float    f32x4;
typedef __attribute__((ext_vector_type(8))) _Float16 f16x8;

// Packed tiled layouts (built in workspace):
//  Ep: [t=row/128][step=k/32][512 chunks of 16B]  chunk p = r*4 + (sub ^ ((r>>2)&3))
//      holds rows r=0..127 x k=step*32+sub*8+0..7 as fp16.  Every GEMM DMA
//      reads a contiguous 8 KB block; frag reads are 4-way-max in LDS banks.
//  Bp: same structure with n (= output col h) in place of r, from attn_w[:,H:].

// ---- helpers ----------------------------------------------------------------
__device__ __forceinline__ unsigned short f16_bits(float f) {
  union { _Float16 h; unsigned short u; } cv;
  cv.h = (_Float16)f;           // v_cvt_f16_f32, RNE
  return cv.u;
}

// tanh via one v_exp_f32
__device__ __forceinline__ float fast_tanh(float x) {
  x = fminf(15.0f, fmaxf(-15.0f, x));
  float z = __expf(-2.0f * x);
  return (1.0f - z) * __builtin_amdgcn_rcpf(1.0f + z);
}

// async global->LDS, 16B/lane. LDS dest must be wave-uniform base + lane*16.
__device__ __forceinline__ void load_lds16(const void* g, void* l) {
  __builtin_amdgcn_global_load_lds(
      (const __attribute__((address_space(1))) unsigned int*)g,
      (__attribute__((address_space(3))) unsigned int*)l, 16, 0, 0);
}

// ---- K0: pack enc (S,B,H) fp32 -> tiled/swizzled fp16 Ep ---------------------
// grid (32 steps, 512 tiles) x 256 thr. Reads: 8 lanes x 16B contiguous per row
// -> full-line requests. Writes: wave covers contiguous 512B (swizzle permutes
// only within each row's 64B group).
__global__ void convT_kernel(const float* __restrict__ enc,
                             unsigned short* __restrict__ Ep) {
  int step = blockIdx.x, t = blockIdx.y, tid = threadIdx.x;
  const float* src = enc + (size_t)t * 128 * H_DIM + step * 32;
  unsigned short* dst = Ep + ((size_t)t * 32 + step) * 512 * 8;
#pragma unroll
  for (int c = 0; c < 4; ++c) {
    int q = c * 256 + tid;      // 0..1023 = 128 rows x 8 k-quads
    int r = q >> 3, kq = q & 7;
    f32x4 x = *(const f32x4*)(src + (size_t)r * H_DIM + kq * 4);
    ushort4 o;
    o.x = f16_bits(x.x); o.y = f16_bits(x.y);
    o.z = f16_bits(x.z); o.w = f16_bits(x.w);
    int p = (r << 2) | ((kq >> 1) ^ ((r >> 2) & 3));
    *(ushort4*)(dst + p * 8 + (kq & 1) * 4) = o;
  }
}

// ---- K1: hid_proj[b][h] = hidden[b,:] . attn_w[h, 0:H] + attn_b[h] (fp32) ----
__global__ void hidproj_kernel(const float* __restrict__ hidden,
                               const float* __restrict__ attn_w,
                               const float* __restrict__ attn_b,
                               float* __restrict__ hp) {
  int tid = threadIdx.x;
  int hl  = tid >> 4;            // 0..15
  int kp  = tid & 15;            // 16-way k-split
  int h   = blockIdx.x * 16 + hl;
  const f32x4* wrow = (const f32x4*)(attn_w + (size_t)h * (2 * H_DIM)) + kp * 16;
  f32x4 w[16];
#pragma unroll
  for (int j = 0; j < 16; ++j) w[j] = wrow[j];
  float bias = attn_b[h];
  for (int b = 0; b < B_DIM; ++b) {
    const f32x4* xrow = (const f32x4*)(hidden + (size_t)b * H_DIM) + kp * 16;
    float s = 0.f;
#pragma unroll
    for (int j = 0; j < 16; ++j) {
      f32x4 x = xrow[j];
      s = fmaf(w[j].x, x.x, s); s = fmaf(w[j].y, x.y, s);
      s = fmaf(w[j].z, x.z, s); s = fmaf(w[j].w, x.w, s);
    }
    s += __shfl_xor(s, 1); s += __shfl_xor(s, 2);
    s += __shfl_xor(s, 4); s += __shfl_xor(s, 8);
    if (kp == 0) hp[(size_t)b * H_DIM + h] = s + bias;
  }
}

// ---- K2: pack W2 = attn_w[:, H:2H] to tiled/swizzled fp16 Bp -----------------
// One 16B output chunk per thread; writes fully coalesced, reads 32B segments.
__global__ void packW2_kernel(const float* __restrict__ attn_w,
                              unsigned short* __restrict__ Bp) {
  int c2 = blockIdx.x * 256 + threadIdx.x;   // 131072 chunks
  int ps   = c2 & 3;
  int n    = (c2 >> 2) & 127;
  int step = (c2 >> 9) & 31;
  int g    = c2 >> 14;
  int sub  = ps ^ ((n >> 2) & 3);
  int h    = g * 128 + n;
  int k    = step * 32 + sub * 8;
  const float* src = attn_w + (size_t)h * (2 * H_DIM) + H_DIM + k;
  f32x4 a = *(const f32x4*)src;
  f32x4 b = *(const f32x4*)(src + 4);
  ushort4 lo, hi;
  lo.x = f16_bits(a.x); lo.y = f16_bits(a.y); lo.z = f16_bits(a.z); lo.w = f16_bits(a.w);
  hi.x = f16_bits(b.x); hi.y = f16_bits(b.y); hi.z = f16_bits(b.z); hi.w = f16_bits(b.w);
  *(ushort4*)(Bp + (size_t)c2 * 8)     = lo;
  *(ushort4*)(Bp + (size_t)c2 * 8 + 4) = hi;
}

// ---- K3: fused GEMM(enc x W2^T) + tanh + dot-v -> scores (atomic partials) ---
// 128x128 tile, 256 thr = 4 waves (2x2), wave 64x64 via 4x4 16x16x32 f16 frags.
// Every DMA instruction reads contiguous 1 KB (pre-transposed global layout).
__global__ __launch_bounds__(256, 4)
void gemm_scores_kernel(const unsigned short* __restrict__ Ep,
                        const unsigned short* __restrict__ Bp,
                        const float* __restrict__ hp,
                        const float* __restrict__ v,
                        float* __restrict__ scores) {
  __shared__ __align__(16) unsigned short As[512 * 8];   // 8 KiB
  __shared__ __align__(16) unsigned short Bs[512 * 8];   // 8 KiB
  const int tid  = threadIdx.x;
  const int lane = tid & 63;
  const int wid  = tid >> 6;
  const int wm   = wid >> 1;       // row half (0..1)
  const int wn   = wid & 1;        // col half (0..1)
  const int m16  = lane & 15;
  const int quad = lane >> 4;
  const int g = blockIdx.x;        // col tile (0..7)  -> id%8 pins B-tile to XCD
  const int t = blockIdx.y;        // row tile (0..511)

  // frag LDS offsets (shorts): chunk p = idx*4 + (quad ^ ((idx>>2)&3))
  int aoff[4], boff[4];
#pragma unroll
  for (int f = 0; f < 4; ++f) {
    int r = wm * 64 + f * 16 + m16;
    aoff[f] = ((r << 2) | (quad ^ ((r >> 2) & 3))) * 8;
    int n = wn * 64 + f * 16 + m16;
    boff[f] = ((n << 2) | (quad ^ ((n >> 2) & 3))) * 8;
  }

  f32x4 acc[4][4];
#pragma unroll
  for (int i = 0; i < 4; ++i)
#pragma unroll
    for (int j = 0; j < 4; ++j) acc[i][j] = (f32x4){0.f, 0.f, 0.f, 0.f};

  const unsigned short* aBase = Ep + (size_t)t * 32 * 4096;
  const unsigned short* bBase = Bp + (size_t)g * 32 * 4096;

  for (int step = 0; step < 32; ++step) {
    const unsigned short* aS = aBase + (size_t)step * 4096;
    const unsigned short* bS = bBase + (size_t)step * 4096;
    load_lds16(aS + (size_t)tid * 8,         As + tid * 8);
    load_lds16(aS + (size_t)(256 + tid) * 8, As + (256 + tid) * 8);
    load_lds16(bS + (size_t)tid * 8,         Bs + tid * 8);
    load_lds16(bS + (size_t)(256 + tid) * 8, Bs + (256 + tid) * 8);
    __syncthreads();

    f16x8 af[4], bfr[4];
#pragma unroll
    for (int f = 0; f < 4; ++f) af[f]  = *(const f16x8*)&As[aoff[f]];
#pragma unroll
    for (int f = 0; f < 4; ++f) bfr[f] = *(const f16x8*)&Bs[boff[f]];
#pragma unroll
    for (int mf = 0; mf < 4; ++mf)
#pragma unroll
      for (int nf = 0; nf < 4; ++nf)
        acc[mf][nf] = __builtin_amdgcn_mfma_f32_16x16x32_f16(
            af[mf], bfr[nf], acc[mf][nf], 0, 0, 0);
    __syncthreads();
  }

  // Epilogue: energy = tanh(acc + hid_proj(incl bias)); partial score =
  // sum over this wave's 64 cols of energy*v. C/D: col=lane&15, row=quad*4+reg.
  const int row0 = t * 128, n0 = g * 128;
#pragma unroll
  for (int mf = 0; mf < 4; ++mf) {
#pragma unroll
    for (int reg = 0; reg < 4; ++reg) {
      int row_g = row0 + wm * 64 + mf * 16 + quad * 4 + reg;
      int b     = row_g & 31;     // row = s*32 + b
      int s     = row_g >> 5;
      float psum = 0.f;
#pragma unroll
      for (int nf = 0; nf < 4; ++nf) {
        int col = n0 + wn * 64 + nf * 16 + m16;
        float e = acc[mf][nf][reg] + hp[b * H_DIM + col];
        e = fast_tanh(e);
        psum = fmaf(e, v[col], psum);
      }
      psum += __shfl_xor(psum, 1);
      psum += __shfl_xor(psum, 2);
      psum += __shfl_xor(psum, 4);
      psum += __shfl_xor(psum, 8);
      if (m16 == 0) atomicAdd(&scores[b * S_DIM + s], psum);
    }
  }
}

// ---- K4: masked softmax over s per batch row -> attention weights ------------
__global__ void softmax_kernel(const float* __restrict__ scores,
                               const int* __restrict__ lens,
                               float* __restrict__ wout) {
  int b = blockIdx.x, tid = threadIdx.x;
  int len = lens[b];
  float vals[8];
  float m = -3.0e38f;
#pragma unroll
  for (int i = 0; i < 8; ++i) {
    int s = i * 256 + tid;
    float x = scores[b * S_DIM + s];
    vals[i] = (s < len) ? x : -3.0e38f;
    m = fmaxf(m, vals[i]);
  }
#pragma unroll
  for (int off = 32; off > 0; off >>= 1) m = fmaxf(m, __shfl_xor(m, off));
  __shared__ float redm[4], reds[4];
  int wid = tid >> 6, lane = tid & 63;
  if (lane == 0) redm[wid] = m;
  __syncthreads();
  m = fmaxf(fmaxf(redm[0], redm[1]), fmaxf(redm[2], redm[3]));

  float e[8];
  float sum = 0.f;
#pragma unroll
  for (int i = 0; i < 8; ++i) {
    int s = i * 256 + tid;
    e[i] = (s < len) ? __expf(vals[i] - m) : 0.f;  // masked -> exactly 0
    sum += e[i];
  }
#pragma unroll
  for (int off = 32; off > 0; off >>= 1) sum += __shfl_xor(sum, off);
  if (lane == 0) reds[wid] = sum;
  __syncthreads();
  sum = reds[0] + reds[1] + reds[2] + reds[3];
  float inv = 1.0f / sum;
#pragma unroll
  for (int i = 0; i < 8; ++i)
    wout[b * S_DIM + i * 256 + tid] = e[i] * inv;
}

// ---- K5: context[b][h] = sum_s w[b][s] * enc[s][b][h]  (fp32 enc, coalesced) -
__global__ void context_kernel(const float* __restrict__ enc,
                               const float* __restrict__ wts,
                               const int* __restrict__ lens,
                               float* __restrict__ ctx) {
  int sc = blockIdx.x;            // 32 chunks of 64 s
  int b  = blockIdx.y;
  int len = lens[b];
  int s0 = sc * 64;
  if (s0 >= len) return;          // fully masked chunk (weights exactly 0)
  int cnt = min(64, len - s0);
  int tid = threadIdx.x;          // 256 threads x 4 h = 1024
  f32x4 acc = (f32x4){0.f, 0.f, 0.f, 0.f};
  const float* wrow = wts + (size_t)b * S_DIM + s0;
#pragma unroll 4
  for (int i = 0; i < cnt; ++i) {
    float w = wrow[i];
    f32x4 e = *(const f32x4*)(enc + ((size_t)(s0 + i) * B_DIM + b) * H_DIM + tid * 4);
    acc.x = fmaf(w, e.x, acc.x);
    acc.y = fmaf(w, e.y, acc.y);
    acc.z = fmaf(w, e.z, acc.z);
    acc.w = fmaf(w, e.w, acc.w);
  }
  float* dst = ctx + (size_t)b * H_DIM + tid * 4;
  atomicAdd(dst + 0, acc.x);
  atomicAdd(dst + 1, acc.y);
  atomicAdd(dst + 2, acc.z);
  atomicAdd(dst + 3, acc.w);
}

// ---- launch -----------------------------------------------------------------
extern "C" void kernel_launch(void* const* d_in, const int* in_sizes, int n_in,
                              void* d_out, int out_size, void* d_ws, size_t ws_size,
                              hipStream_t stream) {
  const float* hidden = (const float*)d_in[0];   // (B,H)
  const float* enc    = (const float*)d_in[1];   // (S,B,H)
  const int*   lens   = (const int*)d_in[2];     // (B,)
  const float* attn_w = (const float*)d_in[3];   // (H,2H)
  const float* attn_b = (const float*)d_in[4];   // (H,)
  const float* v      = (const float*)d_in[5];   // (H,)

  float* out_ctx = (float*)d_out;                      // B*H context
  float* out_w   = (float*)d_out + B_DIM * H_DIM;      // B*S weights

  // ws: Ep fp16 tiled (128 MiB) | scores | hp | Bp fp16 tiled (2 MiB)
  char* p = (char*)d_ws;
  unsigned short* Ep = (unsigned short*)p; p += (size_t)ROWS * H_DIM * 2;
  float* scores = (float*)p;               p += (size_t)B_DIM * S_DIM * 4;
  float* hp     = (float*)p;               p += (size_t)B_DIM * H_DIM * 4;
  unsigned short* Bp = (unsigned short*)p;

  hipMemsetAsync(scores, 0, (size_t)B_DIM * S_DIM * sizeof(float), stream);
  hipMemsetAsync(out_ctx, 0, (size_t)B_DIM * H_DIM * sizeof(float), stream);

  hipLaunchKernelGGL(convT_kernel, dim3(32, ROWS / 128), dim3(256), 0, stream,
                     enc, Ep);
  hipLaunchKernelGGL(hidproj_kernel, dim3(H_DIM / 16), dim3(256), 0, stream,
                     hidden, attn_w, attn_b, hp);
  hipLaunchKernelGGL(packW2_kernel, dim3(512), dim3(256), 0, stream,
                     attn_w, Bp);
  hipLaunchKernelGGL(gemm_scores_kernel, dim3(H_DIM / 128, ROWS / 128),
                     dim3(256), 0, stream, Ep, Bp, hp, v, scores);
  hipLaunchKernelGGL(softmax_kernel, dim3(B_DIM), dim3(256), 0, stream,
                     scores, lens, out_w);
  hipLaunchKernelGGL(context_kernel, dim3(S_DIM / 64, B_DIM), dim3(256), 0, stream,
                     enc, out_w, lens, out_ctx);
}

// Round 4
// 702.212 us; speedup vs baseline: 1.2164x; 1.1475x over previous
//
#include <hip/hip_runtime.h>

// Problem dims (fixed by reference)
#define S_DIM 2048
#define B_DIM 32
#define H_DIM 1024
#define ROWS  (S_DIM * B_DIM)   // 65536 GEMM rows, row = s*32 + b

typedef __attribute__((ext_vector_type(4))) float    f32x4;
typedef __attribute__((ext_vector_type(8))) _Float16 f16x8;

// Packed tiled layouts (built in workspace):
//  Ep: [t=row/128][step=k/32][512 chunks of 16B]  chunk p = r*4 + (sub ^ ((r>>2)&3))
//      holds rows r=0..127 x k=step*32+sub*8+0..7 as fp16.  Every GEMM DMA
//      reads a contiguous 8 KB block; frag reads are 4-way-max in LDS banks.
//  Bp: same structure with n (= output col h) in place of r, from attn_w[:,H:].

// ---- helpers ----------------------------------------------------------------
__device__ __forceinline__ unsigned short f16_bits(float f) {
  union { _Float16 h; unsigned short u; } cv;
  cv.h = (_Float16)f;           // v_cvt_f16_f32, RNE
  return cv.u;
}

// tanh via one v_exp_f32
__device__ __forceinline__ float fast_tanh(float x) {
  x = fminf(15.0f, fmaxf(-15.0f, x));
  float z = __expf(-2.0f * x);
  return (1.0f - z) * __builtin_amdgcn_rcpf(1.0f + z);
}

// async global->LDS, 16B/lane. LDS dest must be wave-uniform base + lane*16.
__device__ __forceinline__ void load_lds16(const void* g, void* l) {
  __builtin_amdgcn_global_load_lds(
      (const __attribute__((address_space(1))) unsigned int*)g,
      (__attribute__((address_space(3))) unsigned int*)l, 16, 0, 0);
}

// ---- K0: pack enc (S,B,H) fp32 -> tiled/swizzled fp16 Ep ---------------------
__global__ void convT_kernel(const float* __restrict__ enc,
                             unsigned short* __restrict__ Ep) {
  int step = blockIdx.x, t = blockIdx.y, tid = threadIdx.x;
  const float* src = enc + (size_t)t * 128 * H_DIM + step * 32;
  unsigned short* dst = Ep + ((size_t)t * 32 + step) * 512 * 8;
#pragma unroll
  for (int c = 0; c < 4; ++c) {
    int q = c * 256 + tid;      // 0..1023 = 128 rows x 8 k-quads
    int r = q >> 3, kq = q & 7;
    f32x4 x = *(const f32x4*)(src + (size_t)r * H_DIM + kq * 4);
    ushort4 o;
    o.x = f16_bits(x.x); o.y = f16_bits(x.y);
    o.z = f16_bits(x.z); o.w = f16_bits(x.w);
    int p = (r << 2) | ((kq >> 1) ^ ((r >> 2) & 3));
    *(ushort4*)(dst + p * 8 + (kq & 1) * 4) = o;
  }
}

// ---- K1: hid_proj[b][h] = hidden[b,:] . attn_w[h, 0:H] + attn_b[h] (fp32) ----
__global__ void hidproj_kernel(const float* __restrict__ hidden,
                               const float* __restrict__ attn_w,
                               const float* __restrict__ attn_b,
                               float* __restrict__ hp) {
  int tid = threadIdx.x;
  int hl  = tid >> 4;            // 0..15
  int kp  = tid & 15;            // 16-way k-split
  int h   = blockIdx.x * 16 + hl;
  const f32x4* wrow = (const f32x4*)(attn_w + (size_t)h * (2 * H_DIM)) + kp * 16;
  f32x4 w[16];
#pragma unroll
  for (int j = 0; j < 16; ++j) w[j] = wrow[j];
  float bias = attn_b[h];
  for (int b = 0; b < B_DIM; ++b) {
    const f32x4* xrow = (const f32x4*)(hidden + (size_t)b * H_DIM) + kp * 16;
    float s = 0.f;
#pragma unroll
    for (int j = 0; j < 16; ++j) {
      f32x4 x = xrow[j];
      s = fmaf(w[j].x, x.x, s); s = fmaf(w[j].y, x.y, s);
      s = fmaf(w[j].z, x.z, s); s = fmaf(w[j].w, x.w, s);
    }
    s += __shfl_xor(s, 1); s += __shfl_xor(s, 2);
    s += __shfl_xor(s, 4); s += __shfl_xor(s, 8);
    if (kp == 0) hp[(size_t)b * H_DIM + h] = s + bias;
  }
}

// ---- K2: pack W2 = attn_w[:, H:2H] to tiled/swizzled fp16 Bp -----------------
__global__ void packW2_kernel(const float* __restrict__ attn_w,
                              unsigned short* __restrict__ Bp) {
  int c2 = blockIdx.x * 256 + threadIdx.x;   // 131072 chunks
  int ps   = c2 & 3;
  int n    = (c2 >> 2) & 127;
  int step = (c2 >> 9) & 31;
  int g    = c2 >> 14;
  int sub  = ps ^ ((n >> 2) & 3);
  int h    = g * 128 + n;
  int k    = step * 32 + sub * 8;
  const float* src = attn_w + (size_t)h * (2 * H_DIM) + H_DIM + k;
  f32x4 a = *(const f32x4*)src;
  f32x4 b = *(const f32x4*)(src + 4);
  ushort4 lo, hi;
  lo.x = f16_bits(a.x); lo.y = f16_bits(a.y); lo.z = f16_bits(a.z); lo.w = f16_bits(a.w);
  hi.x = f16_bits(b.x); hi.y = f16_bits(b.y); hi.z = f16_bits(b.z); hi.w = f16_bits(b.w);
  *(ushort4*)(Bp + (size_t)c2 * 8)     = lo;
  *(ushort4*)(Bp + (size_t)c2 * 8 + 4) = hi;
}

// ---- K3: fused GEMM(enc x W2^T) + tanh + dot-v -> scores (atomic partials) ---
// 128x128 tile, 256 thr = 4 waves (2x2), wave 64x64 via 4x4 16x16x32 f16 frags.
// 1-D grid of 4096 with XCD-colocation decode: the 8 blocks sharing a row
// tile get ids = xcd + 8*(...)  -> same XCD (id%8 round-robin), adjacent in
// dispatch order -> A tile fetched once per XCD, re-served from its L2.
__global__ __launch_bounds__(256, 4)
void gemm_scores_kernel(const unsigned short* __restrict__ Ep,
                        const unsigned short* __restrict__ Bp,
                        const float* __restrict__ hp,
                        const float* __restrict__ v,
                        float* __restrict__ scores) {
  __shared__ __align__(16) unsigned short As[512 * 8];   // 8 KiB
  __shared__ __align__(16) unsigned short Bs[512 * 8];   // 8 KiB
  const int tid  = threadIdx.x;
  const int lane = tid & 63;
  const int wid  = tid >> 6;
  const int wm   = wid >> 1;       // row half (0..1)
  const int wn   = wid & 1;        // col half (0..1)
  const int m16  = lane & 15;
  const int quad = lane >> 4;
  // XCD-colocating decode
  const int bid  = blockIdx.x;
  const int xcd  = bid & 7;
  const int slot = bid >> 3;            // 0..511
  const int t    = xcd * 64 + (slot >> 3);  // row tile 0..511
  const int g    = slot & 7;                // col tile 0..7

  // frag LDS offsets (shorts): chunk p = idx*4 + (quad ^ ((idx>>2)&3))
  int aoff[4], boff[4];
#pragma unroll
  for (int f = 0; f < 4; ++f) {
    int r = wm * 64 + f * 16 + m16;
    aoff[f] = ((r << 2) | (quad ^ ((r >> 2) & 3))) * 8;
    int n = wn * 64 + f * 16 + m16;
    boff[f] = ((n << 2) | (quad ^ ((n >> 2) & 3))) * 8;
  }

  f32x4 acc[4][4];
#pragma unroll
  for (int i = 0; i < 4; ++i)
#pragma unroll
    for (int j = 0; j < 4; ++j) acc[i][j] = (f32x4){0.f, 0.f, 0.f, 0.f};

  const unsigned short* aBase = Ep + (size_t)t * 32 * 4096;
  const unsigned short* bBase = Bp + (size_t)g * 32 * 4096;

  for (int step = 0; step < 32; ++step) {
    const unsigned short* aS = aBase + (size_t)step * 4096;
    const unsigned short* bS = bBase + (size_t)step * 4096;
    load_lds16(aS + (size_t)tid * 8,         As + tid * 8);
    load_lds16(aS + (size_t)(256 + tid) * 8, As + (256 + tid) * 8);
    load_lds16(bS + (size_t)tid * 8,         Bs + tid * 8);
    load_lds16(bS + (size_t)(256 + tid) * 8, Bs + (256 + tid) * 8);
    __syncthreads();

    f16x8 af[4], bfr[4];
#pragma unroll
    for (int f = 0; f < 4; ++f) af[f]  = *(const f16x8*)&As[aoff[f]];
#pragma unroll
    for (int f = 0; f < 4; ++f) bfr[f] = *(const f16x8*)&Bs[boff[f]];
#pragma unroll
    for (int mf = 0; mf < 4; ++mf)
#pragma unroll
      for (int nf = 0; nf < 4; ++nf)
        acc[mf][nf] = __builtin_amdgcn_mfma_f32_16x16x32_f16(
            af[mf], bfr[nf], acc[mf][nf], 0, 0, 0);
    __syncthreads();
  }

  // Epilogue: energy = tanh(acc + hid_proj(incl bias)); partial score =
  // sum over this wave's 64 cols of energy*v. C/D: col=lane&15, row=quad*4+reg.
  const int row0 = t * 128, n0 = g * 128;
#pragma unroll
  for (int mf = 0; mf < 4; ++mf) {
#pragma unroll
    for (int reg = 0; reg < 4; ++reg) {
      int row_g = row0 + wm * 64 + mf * 16 + quad * 4 + reg;
      int b     = row_g & 31;     // row = s*32 + b
      int s     = row_g >> 5;
      float psum = 0.f;
#pragma unroll
      for (int nf = 0; nf < 4; ++nf) {
        int col = n0 + wn * 64 + nf * 16 + m16;
        float e = acc[mf][nf][reg] + hp[b * H_DIM + col];
        e = fast_tanh(e);
        psum = fmaf(e, v[col], psum);
      }
      psum += __shfl_xor(psum, 1);
      psum += __shfl_xor(psum, 2);
      psum += __shfl_xor(psum, 4);
      psum += __shfl_xor(psum, 8);
      if (m16 == 0) atomicAdd(&scores[b * S_DIM + s], psum);
    }
  }
}

// ---- K4: masked softmax over s per batch row -> attention weights ------------
__global__ void softmax_kernel(const float* __restrict__ scores,
                               const int* __restrict__ lens,
                               float* __restrict__ wout) {
  int b = blockIdx.x, tid = threadIdx.x;
  int len = lens[b];
  float vals[8];
  float m = -3.0e38f;
#pragma unroll
  for (int i = 0; i < 8; ++i) {
    int s = i * 256 + tid;
    float x = scores[b * S_DIM + s];
    vals[i] = (s < len) ? x : -3.0e38f;
    m = fmaxf(m, vals[i]);
  }
#pragma unroll
  for (int off = 32; off > 0; off >>= 1) m = fmaxf(m, __shfl_xor(m, off));
  __shared__ float redm[4], reds[4];
  int wid = tid >> 6, lane = tid & 63;
  if (lane == 0) redm[wid] = m;
  __syncthreads();
  m = fmaxf(fmaxf(redm[0], redm[1]), fmaxf(redm[2], redm[3]));

  float e[8];
  float sum = 0.f;
#pragma unroll
  for (int i = 0; i < 8; ++i) {
    int s = i * 256 + tid;
    e[i] = (s < len) ? __expf(vals[i] - m) : 0.f;  // masked -> exactly 0
    sum += e[i];
  }
#pragma unroll
  for (int off = 32; off > 0; off >>= 1) sum += __shfl_xor(sum, off);
  if (lane == 0) reds[wid] = sum;
  __syncthreads();
  sum = reds[0] + reds[1] + reds[2] + reds[3];
  float inv = 1.0f / sum;
#pragma unroll
  for (int i = 0; i < 8; ++i)
    wout[b * S_DIM + i * 256 + tid] = e[i] * inv;
}

// ---- K5: context[b][h] = sum_s w[b][s] * enc[s][b][h], reading packed fp16 Ep
// b-paired blocks: waves 0,1 handle b0, waves 2,3 handle b0+1 -> rows r,r+1
// -> full 128B-line utilization. Masking is wave-uniform (prefix property).
__global__ void context_kernel(const unsigned short* __restrict__ Ep,
                               const float* __restrict__ wts,
                               const int* __restrict__ lens,
                               float* __restrict__ ctx) {
  int sc = blockIdx.x;                 // 0..31, 64 s each
  int b0 = blockIdx.y * 2;
  int tid = threadIdx.x;
  int bb = tid >> 7;                   // wave-uniform (waves 0,1 vs 2,3)
  int c  = tid & 127;                  // h-chunk 0..127 (8 h each)
  int b  = b0 + bb;
  int len = lens[b];
  int s0 = sc * 64;
  if (s0 >= len) return;               // wave-uniform exit (weights all 0)
  int cnt = min(64, len - s0);
  int step = c >> 2, sub = c & 3;
  int hb = step * 32 + sub * 8;
  float acc[8] = {0.f, 0.f, 0.f, 0.f, 0.f, 0.f, 0.f, 0.f};
  const float* wrow = wts + (size_t)b * S_DIM + s0;
  for (int i = 0; i < cnt; ++i) {
    int s = s0 + i;
    float w = wrow[i];
    int R = s * 32 + b;
    int t = R >> 7, r = R & 127;
    size_t chunk = ((size_t)t * 32 + step) * 512 + (r << 2) + (sub ^ ((r >> 2) & 3));
    f16x8 e = *(const f16x8*)(Ep + chunk * 8);
#pragma unroll
    for (int j = 0; j < 8; ++j) acc[j] = fmaf(w, (float)e[j], acc[j]);
  }
  float* dst = ctx + (size_t)b * H_DIM + hb;
#pragma unroll
  for (int j = 0; j < 8; ++j) atomicAdd(dst + j, acc[j]);
}

// ---- launch -----------------------------------------------------------------
extern "C" void kernel_launch(void* const* d_in, const int* in_sizes, int n_in,
                              void* d_out, int out_size, void* d_ws, size_t ws_size,
                              hipStream_t stream) {
  const float* hidden = (const float*)d_in[0];   // (B,H)
  const float* enc    = (const float*)d_in[1];   // (S,B,H)
  const int*   lens   = (const int*)d_in[2];     // (B,)
  const float* attn_w = (const float*)d_in[3];   // (H,2H)
  const float* attn_b = (const float*)d_in[4];   // (H,)
  const float* v      = (const float*)d_in[5];   // (H,)

  float* out_ctx = (float*)d_out;                      // B*H context
  float* out_w   = (float*)d_out + B_DIM * H_DIM;      // B*S weights

  // ws: Ep fp16 tiled (128 MiB) | scores | hp | Bp fp16 tiled (2 MiB)
  char* p = (char*)d_ws;
  unsigned short* Ep = (unsigned short*)p; p += (size_t)ROWS * H_DIM * 2;
  float* scores = (float*)p;               p += (size_t)B_DIM * S_DIM * 4;
  float* hp     = (float*)p;               p += (size_t)B_DIM * H_DIM * 4;
  unsigned short* Bp = (unsigned short*)p;

  hipMemsetAsync(scores, 0, (size_t)B_DIM * S_DIM * sizeof(float), stream);
  hipMemsetAsync(out_ctx, 0, (size_t)B_DIM * H_DIM * sizeof(float), stream);

  hipLaunchKernelGGL(convT_kernel, dim3(32, ROWS / 128), dim3(256), 0, stream,
                     enc, Ep);
  hipLaunchKernelGGL(hidproj_kernel, dim3(H_DIM / 16), dim3(256), 0, stream,
                     hidden, attn_w, attn_b, hp);
  hipLaunchKernelGGL(packW2_kernel, dim3(512), dim3(256), 0, stream,
                     attn_w, Bp);
  hipLaunchKernelGGL(gemm_scores_kernel, dim3(4096), dim3(256), 0, stream,
                     Ep, Bp, hp, v, scores);
  hipLaunchKernelGGL(softmax_kernel, dim3(B_DIM), dim3(256), 0, stream,
                     scores, lens, out_w);
  hipLaunchKernelGGL(context_kernel, dim3(S_DIM / 64, B_DIM / 2), dim3(256),
                     0, stream, Ep, out_w, lens, out_ctx);
}

// Round 5
// 663.839 us; speedup vs baseline: 1.2867x; 1.0578x over previous
//
#include <hip/hip_runtime.h>

// Problem dims (fixed by reference)
#define S_DIM 2048
#define B_DIM 32
#define H_DIM 1024
#define ROWS  (S_DIM * B_DIM)   // 65536 GEMM rows, row = s*32 + b

typedef __attribute__((ext_vector_type(4))) float    f32x4;
typedef __attribute__((ext_vector_type(8))) _Float16 f16x8;

// Packed tiled fp16 layouts (built in workspace), BK=64:
//  Ep: [t=row/128][step=k/64][1024 chunks of 16B], chunk p = r*8 + (sub ^ (r&7))
//      where sub = (k%64)/8. Every GEMM DMA reads contiguous 16B*lane; frag
//      ds_read_b128 is bank-conflict-free: within 8 consecutive lanes the 8
//      slots are distinct -> bank starts {0,4,..,28} cover all 32 banks once.
//  Bp: same with n (= output col h) in place of r, from attn_w[:,H:].

// ---- helpers ----------------------------------------------------------------
__device__ __forceinline__ unsigned short f16_bits(float f) {
  union { _Float16 h; unsigned short u; } cv;
  cv.h = (_Float16)f;           // v_cvt_f16_f32, RNE
  return cv.u;
}

// tanh via one v_exp_f32
__device__ __forceinline__ float fast_tanh(float x) {
  x = fminf(15.0f, fmaxf(-15.0f, x));
  float z = __expf(-2.0f * x);
  return (1.0f - z) * __builtin_amdgcn_rcpf(1.0f + z);
}

// async global->LDS, 16B/lane. LDS dest must be wave-uniform base + lane*16.
__device__ __forceinline__ void load_lds16(const void* g, void* l) {
  __builtin_amdgcn_global_load_lds(
      (const __attribute__((address_space(1))) unsigned int*)g,
      (__attribute__((address_space(3))) unsigned int*)l, 16, 0, 0);
}

// ---- K0: pack enc (S,B,H) fp32 -> tiled/swizzled fp16 Ep (BK=64 layout) ------
// grid (16 steps, 512 tiles) x 256 thr, 4 chunks/thread. Reads: 8-lane groups
// cover one row's 64 k = 256B contiguous (permuted within). Writes contiguous.
__global__ void convT_kernel(const float* __restrict__ enc,
                             unsigned short* __restrict__ Ep) {
  int step = blockIdx.x, t = blockIdx.y, tid = threadIdx.x;
  const float* src = enc + (size_t)t * 128 * H_DIM + step * 64;
  unsigned short* dst = Ep + (((size_t)t * 16 + step) * 1024) * 8;
#pragma unroll
  for (int c = 0; c < 4; ++c) {
    int q = c * 256 + tid;        // chunk index 0..1023
    int r = q >> 3, slot = q & 7;
    int sub = slot ^ (r & 7);
    const float* s = src + (size_t)r * H_DIM + sub * 8;
    f32x4 a = *(const f32x4*)s;
    f32x4 b = *(const f32x4*)(s + 4);
    ushort4 lo, hi;
    lo.x = f16_bits(a.x); lo.y = f16_bits(a.y); lo.z = f16_bits(a.z); lo.w = f16_bits(a.w);
    hi.x = f16_bits(b.x); hi.y = f16_bits(b.y); hi.z = f16_bits(b.z); hi.w = f16_bits(b.w);
    *(ushort4*)(dst + q * 8)     = lo;
    *(ushort4*)(dst + q * 8 + 4) = hi;
  }
}

// ---- K1 (fused prep): hidproj | packW2 | zero scores | zero ctx --------------
// blocks 0..63: hid_proj[b][h] = hidden[b,:].attn_w[h,0:H] + attn_b[h]
// blocks 64..575: pack W2 -> Bp (BK=64 tiled layout)
// blocks 576..639: scores = 0   blocks 640..671: ctx = 0
__global__ void prep_kernel(const float* __restrict__ hidden,
                            const float* __restrict__ attn_w,
                            const float* __restrict__ attn_b,
                            float* __restrict__ hp,
                            unsigned short* __restrict__ Bp,
                            float* __restrict__ scores,
                            float* __restrict__ ctx) {
  int bid = blockIdx.x, tid = threadIdx.x;
  if (bid < 64) {                      // ---- hidproj ----
    int hl = tid >> 4;                 // 0..15
    int kp = tid & 15;                 // 16-way k-split
    int h  = bid * 16 + hl;
    const f32x4* wrow = (const f32x4*)(attn_w + (size_t)h * (2 * H_DIM)) + kp * 16;
    f32x4 w[16];
#pragma unroll
    for (int j = 0; j < 16; ++j) w[j] = wrow[j];
    float bias = attn_b[h];
    for (int b = 0; b < B_DIM; ++b) {
      const f32x4* xrow = (const f32x4*)(hidden + (size_t)b * H_DIM) + kp * 16;
      float s = 0.f;
#pragma unroll
      for (int j = 0; j < 16; ++j) {
        f32x4 x = xrow[j];
        s = fmaf(w[j].x, x.x, s); s = fmaf(w[j].y, x.y, s);
        s = fmaf(w[j].z, x.z, s); s = fmaf(w[j].w, x.w, s);
      }
      s += __shfl_xor(s, 1); s += __shfl_xor(s, 2);
      s += __shfl_xor(s, 4); s += __shfl_xor(s, 8);
      if (kp == 0) hp[(size_t)b * H_DIM + h] = s + bias;
    }
  } else if (bid < 576) {              // ---- packW2 ----
    int id = (bid - 64) * 256 + tid;   // global chunk 0..131071
    int slot = id & 7;
    int n    = (id >> 3) & 127;
    int step = (id >> 10) & 15;
    int g    = id >> 14;
    int sub  = slot ^ (n & 7);
    int h    = g * 128 + n;
    const float* src = attn_w + (size_t)h * (2 * H_DIM) + H_DIM + step * 64 + sub * 8;
    f32x4 a = *(const f32x4*)src;
    f32x4 b = *(const f32x4*)(src + 4);
    ushort4 lo, hi;
    lo.x = f16_bits(a.x); lo.y = f16_bits(a.y); lo.z = f16_bits(a.z); lo.w = f16_bits(a.w);
    hi.x = f16_bits(b.x); hi.y = f16_bits(b.y); hi.z = f16_bits(b.z); hi.w = f16_bits(b.w);
    *(ushort4*)(Bp + (size_t)id * 8)     = lo;
    *(ushort4*)(Bp + (size_t)id * 8 + 4) = hi;
  } else if (bid < 640) {              // ---- zero scores (256 KiB) ----
    int idx = (bid - 576) * 256 + tid;
    *(f32x4*)(scores + (size_t)idx * 4) = (f32x4){0.f, 0.f, 0.f, 0.f};
  } else {                             // ---- zero ctx (128 KiB) ----
    int idx = (bid - 640) * 256 + tid;
    *(f32x4*)(ctx + (size_t)idx * 4) = (f32x4){0.f, 0.f, 0.f, 0.f};
  }
}

// ---- K3: fused GEMM(enc x W2^T) + tanh + dot-v -> scores (atomic partials) ---
// 128x128 tile, BK=64, 256 thr = 4 waves (2x2), wave 64x64 via 4x4 16x16x32 f16
// frags x 2 k-halves. XCD-colocating 1-D grid decode (id%8 = XCD round-robin):
// the 8 blocks sharing a row tile land on one XCD, adjacent in dispatch order.
__global__ __launch_bounds__(256, 4)
void gemm_scores_kernel(const unsigned short* __restrict__ Ep,
                        const unsigned short* __restrict__ Bp,
                        const float* __restrict__ hp,
                        const float* __restrict__ v,
                        float* __restrict__ scores) {
  __shared__ __align__(16) unsigned short As[1024 * 8];   // 16 KiB
  __shared__ __align__(16) unsigned short Bs[1024 * 8];   // 16 KiB
  const int tid  = threadIdx.x;
  const int lane = tid & 63;
  const int wid  = tid >> 6;
  const int wm   = wid >> 1;       // row half (0..1)
  const int wn   = wid & 1;        // col half (0..1)
  const int m16  = lane & 15;
  const int quad = lane >> 4;
  const int rx   = m16 & 7;        // swizzle key (r&7 == m16&7 for all frags)
  // XCD-colocating decode
  const int bid  = blockIdx.x;
  const int xcd  = bid & 7;
  const int slot = bid >> 3;               // 0..511
  const int t    = xcd * 64 + (slot >> 3); // row tile 0..511
  const int g    = slot & 7;               // col tile 0..7

  f32x4 acc[4][4];
#pragma unroll
  for (int i = 0; i < 4; ++i)
#pragma unroll
    for (int j = 0; j < 4; ++j) acc[i][j] = (f32x4){0.f, 0.f, 0.f, 0.f};

  const unsigned short* aBase = Ep + (size_t)t * 16 * 8192;
  const unsigned short* bBase = Bp + (size_t)g * 16 * 8192;

  for (int step = 0; step < 16; ++step) {
    const unsigned short* aS = aBase + (size_t)step * 8192;
    const unsigned short* bS = bBase + (size_t)step * 8192;
#pragma unroll
    for (int c = 0; c < 4; ++c) {
      int q = c * 256 + tid;
      load_lds16(aS + (size_t)q * 8, As + q * 8);
      load_lds16(bS + (size_t)q * 8, Bs + q * 8);
    }
    __syncthreads();

#pragma unroll
    for (int ko = 0; ko < 2; ++ko) {
      int sl = (ko * 4 + quad) ^ rx;            // conflict-free slot
      f16x8 af[4], bfr[4];
#pragma unroll
      for (int f = 0; f < 4; ++f) {
        int r = wm * 64 + f * 16 + m16;
        af[f] = *(const f16x8*)&As[r * 64 + sl * 8];
      }
#pragma unroll
      for (int f = 0; f < 4; ++f) {
        int n = wn * 64 + f * 16 + m16;
        bfr[f] = *(const f16x8*)&Bs[n * 64 + sl * 8];
      }
#pragma unroll
      for (int mf = 0; mf < 4; ++mf)
#pragma unroll
        for (int nf = 0; nf < 4; ++nf)
          acc[mf][nf] = __builtin_amdgcn_mfma_f32_16x16x32_f16(
              af[mf], bfr[nf], acc[mf][nf], 0, 0, 0);
    }
    __syncthreads();
  }

  // Epilogue: energy = tanh(acc + hid_proj(incl bias)); partial score =
  // sum over this wave's 64 cols of energy*v. C/D: col=lane&15, row=quad*4+reg.
  const int row0 = t * 128, n0 = g * 128;
#pragma unroll
  for (int mf = 0; mf < 4; ++mf) {
#pragma unroll
    for (int reg = 0; reg < 4; ++reg) {
      int row_g = row0 + wm * 64 + mf * 16 + quad * 4 + reg;
      int b     = row_g & 31;     // row = s*32 + b
      int s     = row_g >> 5;
      float psum = 0.f;
#pragma unroll
      for (int nf = 0; nf < 4; ++nf) {
        int col = n0 + wn * 64 + nf * 16 + m16;
        float e = acc[mf][nf][reg] + hp[b * H_DIM + col];
        e = fast_tanh(e);
        psum = fmaf(e, v[col], psum);
      }
      psum += __shfl_xor(psum, 1);
      psum += __shfl_xor(psum, 2);
      psum += __shfl_xor(psum, 4);
      psum += __shfl_xor(psum, 8);
      if (m16 == 0) atomicAdd(&scores[b * S_DIM + s], psum);
    }
  }
}

// ---- K4: masked softmax over s per batch row -> attention weights ------------
__global__ void softmax_kernel(const float* __restrict__ scores,
                               const int* __restrict__ lens,
                               float* __restrict__ wout) {
  int b = blockIdx.x, tid = threadIdx.x;
  int len = lens[b];
  float vals[8];
  float m = -3.0e38f;
#pragma unroll
  for (int i = 0; i < 8; ++i) {
    int s = i * 256 + tid;
    float x = scores[b * S_DIM + s];
    vals[i] = (s < len) ? x : -3.0e38f;
    m = fmaxf(m, vals[i]);
  }
#pragma unroll
  for (int off = 32; off > 0; off >>= 1) m = fmaxf(m, __shfl_xor(m, off));
  __shared__ float redm[4], reds[4];
  int wid = tid >> 6, lane = tid & 63;
  if (lane == 0) redm[wid] = m;
  __syncthreads();
  m = fmaxf(fmaxf(redm[0], redm[1]), fmaxf(redm[2], redm[3]));

  float e[8];
  float sum = 0.f;
#pragma unroll
  for (int i = 0; i < 8; ++i) {
    int s = i * 256 + tid;
    e[i] = (s < len) ? __expf(vals[i] - m) : 0.f;  // masked -> exactly 0
    sum += e[i];
  }
#pragma unroll
  for (int off = 32; off > 0; off >>= 1) sum += __shfl_xor(sum, off);
  if (lane == 0) reds[wid] = sum;
  __syncthreads();
  sum = reds[0] + reds[1] + reds[2] + reds[3];
  float inv = 1.0f / sum;
#pragma unroll
  for (int i = 0; i < 8; ++i)
    wout[b * S_DIM + i * 256 + tid] = e[i] * inv;
}

// ---- K5: context[b][h] = sum_s w[b][s] * enc[s][b][h], from packed fp16 Ep ---
// New layout: each (s,b) row's 8 sub-chunks are one contiguous 128B line
// (slot = sub ^ (b&7), loop-invariant). 8-lane groups read full lines.
__global__ void context_kernel(const unsigned short* __restrict__ Ep,
                               const float* __restrict__ wts,
                               const int* __restrict__ lens,
                               float* __restrict__ ctx) {
  int sc = blockIdx.x;                 // 0..31, 64 s each
  int b0 = blockIdx.y * 2;
  int tid = threadIdx.x;
  int bb = tid >> 7;                   // wave-uniform (waves 0,1 vs 2,3)
  int c  = tid & 127;                  // h-chunk 0..127 (8 h each)
  int b  = b0 + bb;
  int len = lens[b];
  int s0 = sc * 64;
  if (s0 >= len) return;               // wave-uniform exit (weights all 0)
  int cnt = min(64, len - s0);
  int step = c >> 3, sub = c & 7;
  int slot = sub ^ (b & 7);            // r&7 == b&7 (rows are s*32+b)
  int hb = step * 64 + sub * 8;
  float acc[8] = {0.f, 0.f, 0.f, 0.f, 0.f, 0.f, 0.f, 0.f};
  const float* wrow = wts + (size_t)b * S_DIM + s0;
  for (int i = 0; i < cnt; ++i) {
    int s = s0 + i;
    float w = wrow[i];
    int t = s >> 2;                    // R = s*32+b; t = R>>7
    int r = (s & 3) * 32 + b;          // r = R&127
    size_t chunk = ((size_t)t * 16 + step) * 1024 + r * 8 + slot;
    f16x8 e = *(const f16x8*)(Ep + chunk * 8);
#pragma unroll
    for (int j = 0; j < 8; ++j) acc[j] = fmaf(w, (float)e[j], acc[j]);
  }
  float* dst = ctx + (size_t)b * H_DIM + hb;
#pragma unroll
  for (int j = 0; j < 8; ++j) atomicAdd(dst + j, acc[j]);
}

// ---- launch -----------------------------------------------------------------
extern "C" void kernel_launch(void* const* d_in, const int* in_sizes, int n_in,
                              void* d_out, int out_size, void* d_ws, size_t ws_size,
                              hipStream_t stream) {
  const float* hidden = (const float*)d_in[0];   // (B,H)
  const float* enc    = (const float*)d_in[1];   // (S,B,H)
  const int*   lens   = (const int*)d_in[2];     // (B,)
  const float* attn_w = (const float*)d_in[3];   // (H,2H)
  const float* attn_b = (const float*)d_in[4];   // (H,)
  const float* v      = (const float*)d_in[5];   // (H,)

  float* out_ctx = (float*)d_out;                      // B*H context
  float* out_w   = (float*)d_out + B_DIM * H_DIM;      // B*S weights

  // ws: Ep fp16 tiled (128 MiB) | scores | hp | Bp fp16 tiled (2 MiB)
  char* p = (char*)d_ws;
  unsigned short* Ep = (unsigned short*)p; p += (size_t)ROWS * H_DIM * 2;
  float* scores = (float*)p;               p += (size_t)B_DIM * S_DIM * 4;
  float* hp     = (float*)p;               p += (size_t)B_DIM * H_DIM * 4;
  unsigned short* Bp = (unsigned short*)p;

  hipLaunchKernelGGL(convT_kernel, dim3(16, ROWS / 128), dim3(256), 0, stream,
                     enc, Ep);
  hipLaunchKernelGGL(prep_kernel, dim3(672), dim3(256), 0, stream,
                     hidden, attn_w, attn_b, hp, Bp, scores, out_ctx);
  hipLaunchKernelGGL(gemm_scores_kernel, dim3(4096), dim3(256), 0, stream,
                     Ep, Bp, hp, v, scores);
  hipLaunchKernelGGL(softmax_kernel, dim3(B_DIM), dim3(256), 0, stream,
                     scores, lens, out_w);
  hipLaunchKernelGGL(context_kernel, dim3(S_DIM / 64, B_DIM / 2), dim3(256),
                     0, stream, Ep, out_w, lens, out_ctx);
}

// Round 7
// 604.764 us; speedup vs baseline: 1.4124x; 1.0977x over previous
//
#include <hip/hip_runtime.h>

// Problem dims (fixed by reference)
#define S_DIM 2048
#define B_DIM 32
#define H_DIM 1024
#define ROWS  (S_DIM * B_DIM)   // 65536 GEMM rows, row = s*32 + b

typedef __attribute__((ext_vector_type(4))) float    f32x4;
typedef __attribute__((ext_vector_type(8))) _Float16 f16x8;
typedef __attribute__((ext_vector_type(2))) __fp16   h16x2;  // cvt_pkrtz result type

// ---- helpers ----------------------------------------------------------------
__device__ __forceinline__ unsigned short f16_bits(float f) {
  union { _Float16 h; unsigned short u; } cv;
  cv.h = (_Float16)f;           // v_cvt_f16_f32, RNE
  return cv.u;
}

// tanh via one v_exp_f32
__device__ __forceinline__ float fast_tanh(float x) {
  x = fminf(15.0f, fmaxf(-15.0f, x));
  float z = __expf(-2.0f * x);
  return (1.0f - z) * __builtin_amdgcn_rcpf(1.0f + z);
}

// async global->LDS, 16B/lane. LDS dest must be wave-uniform base + lane*16.
__device__ __forceinline__ void load_lds16(const void* g, void* l) {
  __builtin_amdgcn_global_load_lds(
      (const __attribute__((address_space(1))) unsigned int*)g,
      (__attribute__((address_space(3))) unsigned int*)l, 16, 0, 0);
}

// ---- K1 (fused prep): hidproj | packW2 | zero scores | zero ctx --------------
// Bp layout (BK=64 tiled, fp16): [g=h/128][step=k/64][1024 chunks of 16B],
// chunk p = n*8 + (sub ^ (n&7)), sub = (k%64)/8 — conflict-free frag reads.
__global__ void prep_kernel(const float* __restrict__ hidden,
                            const float* __restrict__ attn_w,
                            const float* __restrict__ attn_b,
                            float* __restrict__ hp,
                            unsigned short* __restrict__ Bp,
                            float* __restrict__ scores,
                            float* __restrict__ ctx) {
  int bid = blockIdx.x, tid = threadIdx.x;
  if (bid < 64) {                      // ---- hidproj ----
    int hl = tid >> 4;                 // 0..15
    int kp = tid & 15;                 // 16-way k-split
    int h  = bid * 16 + hl;
    const f32x4* wrow = (const f32x4*)(attn_w + (size_t)h * (2 * H_DIM)) + kp * 16;
    f32x4 w[16];
#pragma unroll
    for (int j = 0; j < 16; ++j) w[j] = wrow[j];
    float bias = attn_b[h];
    for (int b = 0; b < B_DIM; ++b) {
      const f32x4* xrow = (const f32x4*)(hidden + (size_t)b * H_DIM) + kp * 16;
      float s = 0.f;
#pragma unroll
      for (int j = 0; j < 16; ++j) {
        f32x4 x = xrow[j];
        s = fmaf(w[j].x, x.x, s); s = fmaf(w[j].y, x.y, s);
        s = fmaf(w[j].z, x.z, s); s = fmaf(w[j].w, x.w, s);
      }
      s += __shfl_xor(s, 1); s += __shfl_xor(s, 2);
      s += __shfl_xor(s, 4); s += __shfl_xor(s, 8);
      if (kp == 0) hp[(size_t)b * H_DIM + h] = s + bias;
    }
  } else if (bid < 576) {              // ---- packW2 ----
    int id = (bid - 64) * 256 + tid;   // global chunk 0..131071
    int slot = id & 7;
    int n    = (id >> 3) & 127;
    int step = (id >> 10) & 15;
    int g    = id >> 14;
    int sub  = slot ^ (n & 7);
    int h    = g * 128 + n;
    const float* src = attn_w + (size_t)h * (2 * H_DIM) + H_DIM + step * 64 + sub * 8;
    f32x4 a = *(const f32x4*)src;
    f32x4 b = *(const f32x4*)(src + 4);
    ushort4 lo, hi;
    lo.x = f16_bits(a.x); lo.y = f16_bits(a.y); lo.z = f16_bits(a.z); lo.w = f16_bits(a.w);
    hi.x = f16_bits(b.x); hi.y = f16_bits(b.y); hi.z = f16_bits(b.z); hi.w = f16_bits(b.w);
    *(ushort4*)(Bp + (size_t)id * 8)     = lo;
    *(ushort4*)(Bp + (size_t)id * 8 + 4) = hi;
  } else if (bid < 640) {              // ---- zero scores (256 KiB) ----
    int idx = (bid - 576) * 256 + tid;
    *(f32x4*)(scores + (size_t)idx * 4) = (f32x4){0.f, 0.f, 0.f, 0.f};
  } else {                             // ---- zero ctx (128 KiB) ----
    int idx = (bid - 640) * 256 + tid;
    *(f32x4*)(ctx + (size_t)idx * 4) = (f32x4){0.f, 0.f, 0.f, 0.f};
  }
}

// ---- K3: fused cvt + GEMM(enc x W2^T) + tanh + dot-v -> scores ---------------
// 128x128 tile, BK=64, 256 thr = 4 waves (2x2), wave 64x64 via 4x4 16x16x32
// f16 frags x 2 k-halves. A is staged fp32->fp16 in-kernel (v_cvt_pkrtz +
// ds_write_b128 into the swizzled layout); no pre-pack pass needed. XCD
// colocation (id%8 = XCD): the 8 blocks sharing a row tile land on one XCD,
// so A is HBM-fetched exactly once chip-wide.
__global__ __launch_bounds__(256, 4)
void gemm_scores_kernel(const float* __restrict__ enc,
                        const unsigned short* __restrict__ Bp,
                        const float* __restrict__ hp,
                        const float* __restrict__ v,
                        float* __restrict__ scores) {
  __shared__ __align__(16) unsigned short As[1024 * 8];   // 16 KiB
  __shared__ __align__(16) unsigned short Bs[1024 * 8];   // 16 KiB
  const int tid  = threadIdx.x;
  const int lane = tid & 63;
  const int wid  = tid >> 6;
  const int wm   = wid >> 1;       // row half (0..1)
  const int wn   = wid & 1;        // col half (0..1)
  const int m16  = lane & 15;
  const int quad = lane >> 4;
  const int rx   = m16 & 7;        // swizzle key (r&7 == m16&7 for all frags)
  // XCD-colocating decode
  const int bid  = blockIdx.x;
  const int xcd  = bid & 7;
  const int slot = bid >> 3;               // 0..511
  const int t    = xcd * 64 + (slot >> 3); // row tile 0..511
  const int g    = slot & 7;               // col tile 0..7

  f32x4 acc[4][4];
#pragma unroll
  for (int i = 0; i < 4; ++i)
#pragma unroll
    for (int j = 0; j < 4; ++j) acc[i][j] = (f32x4){0.f, 0.f, 0.f, 0.f};

  const float* aBase = enc + (size_t)t * 128 * H_DIM;
  const unsigned short* bBase = Bp + (size_t)g * 16 * 8192;

  // Per-thread A-staging indices (4 chunks), loop-invariant parts:
  //   chunk q = c*256+tid; r = q>>3; slot8 = q&7; sub = slot8 ^ (r&7)
  int aR[4], aSub[4];
#pragma unroll
  for (int c = 0; c < 4; ++c) {
    int q = c * 256 + tid;
    aR[c] = q >> 3;
    aSub[c] = (q & 7) ^ (aR[c] & 7);
  }

  for (int step = 0; step < 16; ++step) {
    const unsigned short* bS = bBase + (size_t)step * 8192;
#pragma unroll
    for (int c = 0; c < 4; ++c) {
      int q = c * 256 + tid;
      load_lds16(bS + (size_t)q * 8, Bs + q * 8);
    }
    // A: fp32 load -> cvt_pkrtz -> swizzled LDS
#pragma unroll
    for (int c = 0; c < 4; ++c) {
      int q = c * 256 + tid;
      const float* s = aBase + (size_t)aR[c] * H_DIM + step * 64 + aSub[c] * 8;
      f32x4 a = *(const f32x4*)s;
      f32x4 b = *(const f32x4*)(s + 4);
      union { f16x8 v8; h16x2 h2[4]; } pk;
      pk.h2[0] = __builtin_amdgcn_cvt_pkrtz(a.x, a.y);
      pk.h2[1] = __builtin_amdgcn_cvt_pkrtz(a.z, a.w);
      pk.h2[2] = __builtin_amdgcn_cvt_pkrtz(b.x, b.y);
      pk.h2[3] = __builtin_amdgcn_cvt_pkrtz(b.z, b.w);
      *(f16x8*)(As + q * 8) = pk.v8;
    }
    __syncthreads();

#pragma unroll
    for (int ko = 0; ko < 2; ++ko) {
      int sl = (ko * 4 + quad) ^ rx;            // conflict-free slot
      f16x8 af[4], bfr[4];
#pragma unroll
      for (int f = 0; f < 4; ++f) {
        int r = wm * 64 + f * 16 + m16;
        af[f] = *(const f16x8*)&As[r * 64 + sl * 8];
      }
#pragma unroll
      for (int f = 0; f < 4; ++f) {
        int n = wn * 64 + f * 16 + m16;
        bfr[f] = *(const f16x8*)&Bs[n * 64 + sl * 8];
      }
#pragma unroll
      for (int mf = 0; mf < 4; ++mf)
#pragma unroll
        for (int nf = 0; nf < 4; ++nf)
          acc[mf][nf] = __builtin_amdgcn_mfma_f32_16x16x32_f16(
              af[mf], bfr[nf], acc[mf][nf], 0, 0, 0);
    }
    __syncthreads();
  }

  // Epilogue: energy = tanh(acc + hid_proj(incl bias)); partial score =
  // sum over this wave's 64 cols of energy*v. C/D: col=lane&15, row=quad*4+reg.
  const int row0 = t * 128, n0 = g * 128;
#pragma unroll
  for (int mf = 0; mf < 4; ++mf) {
#pragma unroll
    for (int reg = 0; reg < 4; ++reg) {
      int row_g = row0 + wm * 64 + mf * 16 + quad * 4 + reg;
      int b     = row_g & 31;     // row = s*32 + b
      int s     = row_g >> 5;
      float psum = 0.f;
#pragma unroll
      for (int nf = 0; nf < 4; ++nf) {
        int col = n0 + wn * 64 + nf * 16 + m16;
        float e = acc[mf][nf][reg] + hp[b * H_DIM + col];
        e = fast_tanh(e);
        psum = fmaf(e, v[col], psum);
      }
      psum += __shfl_xor(psum, 1);
      psum += __shfl_xor(psum, 2);
      psum += __shfl_xor(psum, 4);
      psum += __shfl_xor(psum, 8);
      if (m16 == 0) atomicAdd(&scores[b * S_DIM + s], psum);
    }
  }
}

// ---- K4: masked softmax over s per batch row -> attention weights ------------
__global__ void softmax_kernel(const float* __restrict__ scores,
                               const int* __restrict__ lens,
                               float* __restrict__ wout) {
  int b = blockIdx.x, tid = threadIdx.x;
  int len = lens[b];
  float vals[8];
  float m = -3.0e38f;
#pragma unroll
  for (int i = 0; i < 8; ++i) {
    int s = i * 256 + tid;
    float x = scores[b * S_DIM + s];
    vals[i] = (s < len) ? x : -3.0e38f;
    m = fmaxf(m, vals[i]);
  }
#pragma unroll
  for (int off = 32; off > 0; off >>= 1) m = fmaxf(m, __shfl_xor(m, off));
  __shared__ float redm[4], reds[4];
  int wid = tid >> 6, lane = tid & 63;
  if (lane == 0) redm[wid] = m;
  __syncthreads();
  m = fmaxf(fmaxf(redm[0], redm[1]), fmaxf(redm[2], redm[3]));

  float e[8];
  float sum = 0.f;
#pragma unroll
  for (int i = 0; i < 8; ++i) {
    int s = i * 256 + tid;
    e[i] = (s < len) ? __expf(vals[i] - m) : 0.f;  // masked -> exactly 0
    sum += e[i];
  }
#pragma unroll
  for (int off = 32; off > 0; off >>= 1) sum += __shfl_xor(sum, off);
  if (lane == 0) reds[wid] = sum;
  __syncthreads();
  sum = reds[0] + reds[1] + reds[2] + reds[3];
  float inv = 1.0f / sum;
#pragma unroll
  for (int i = 0; i < 8; ++i)
    wout[b * S_DIM + i * 256 + tid] = e[i] * inv;
}

// ---- K5: context[b][h] = sum_s w[b][s] * enc[s][b][h]  (fp32, full-row reads)
// 16 s-chunks x 32 b; prefix mask -> block-level skip; one 4-KB coalesced row
// read per iteration; 4 atomics per thread at the end.
__global__ void context_kernel(const float* __restrict__ enc,
                               const float* __restrict__ wts,
                               const int* __restrict__ lens,
                               float* __restrict__ ctx) {
  int sc = blockIdx.x;            // 0..15, 128 s each
  int b  = blockIdx.y;
  int len = lens[b];
  int s0 = sc * 128;
  if (s0 >= len) return;          // fully masked chunk (weights exactly 0)
  int cnt = min(128, len - s0);
  int tid = threadIdx.x;          // 256 threads x 4 h = 1024
  f32x4 acc = (f32x4){0.f, 0.f, 0.f, 0.f};
  const float* wrow = wts + (size_t)b * S_DIM + s0;
#pragma unroll 4
  for (int i = 0; i < cnt; ++i) {
    float w = wrow[i];
    f32x4 e = *(const f32x4*)(enc + ((size_t)(s0 + i) * B_DIM + b) * H_DIM + tid * 4);
    acc.x = fmaf(w, e.x, acc.x);
    acc.y = fmaf(w, e.y, acc.y);
    acc.z = fmaf(w, e.z, acc.z);
    acc.w = fmaf(w, e.w, acc.w);
  }
  float* dst = ctx + (size_t)b * H_DIM + tid * 4;
  atomicAdd(dst + 0, acc.x);
  atomicAdd(dst + 1, acc.y);
  atomicAdd(dst + 2, acc.z);
  atomicAdd(dst + 3, acc.w);
}

// ---- launch -----------------------------------------------------------------
extern "C" void kernel_launch(void* const* d_in, const int* in_sizes, int n_in,
                              void* d_out, int out_size, void* d_ws, size_t ws_size,
                              hipStream_t stream) {
  const float* hidden = (const float*)d_in[0];   // (B,H)
  const float* enc    = (const float*)d_in[1];   // (S,B,H)
  const int*   lens   = (const int*)d_in[2];     // (B,)
  const float* attn_w = (const float*)d_in[3];   // (H,2H)
  const float* attn_b = (const float*)d_in[4];   // (H,)
  const float* v      = (const float*)d_in[5];   // (H,)

  float* out_ctx = (float*)d_out;                      // B*H context
  float* out_w   = (float*)d_out + B_DIM * H_DIM;      // B*S weights

  // ws: scores (256 KiB) | hp (128 KiB) | Bp fp16 tiled (2 MiB)
  char* p = (char*)d_ws;
  float* scores = (float*)p;               p += (size_t)B_DIM * S_DIM * 4;
  float* hp     = (float*)p;               p += (size_t)B_DIM * H_DIM * 4;
  unsigned short* Bp = (unsigned short*)p;

  hipLaunchKernelGGL(prep_kernel, dim3(672), dim3(256), 0, stream,
                     hidden, attn_w, attn_b, hp, Bp, scores, out_ctx);
  hipLaunchKernelGGL(gemm_scores_kernel, dim3(4096), dim3(256), 0, stream,
                     enc, Bp, hp, v, scores);
  hipLaunchKernelGGL(softmax_kernel, dim3(B_DIM), dim3(256), 0, stream,
                     scores, lens, out_w);
  hipLaunchKernelGGL(context_kernel, dim3(16, B_DIM), dim3(256), 0, stream,
                     enc, out_w, lens, out_ctx);
}